// Round 12
// baseline (1780.196 us; speedup 1.0000x reference)
//
#include <hip/hip_runtime.h>
#include <hip/hip_bf16.h>
#include <stdint.h>

// Problem constants
#define B_ 1024
#define T_ 64
#define D_ 256
#define H_ 256
#define G_ 1024   // 4*H

typedef float f32x4 __attribute__((ext_vector_type(4)));
typedef __bf16 bf16x8 __attribute__((ext_vector_type(8)));
typedef unsigned int u32x4 __attribute__((ext_vector_type(4)));

#if __has_builtin(__builtin_amdgcn_rcpf)
#define RCP(x) __builtin_amdgcn_rcpf(x)
#else
#define RCP(x) (1.f / (x))
#endif

__device__ __forceinline__ unsigned short f2bf(float f) {
    __hip_bfloat16 h = __float2bfloat16(f);   // RNE
    return __builtin_bit_cast(unsigned short, h);
}

// ---------------------------------------------------------------------------
__global__ void prep_w_kernel(const float* __restrict__ Wih, const float* __restrict__ Whh,
                              const float* __restrict__ bih, const float* __restrict__ bhh,
                              unsigned short* __restrict__ wih_bf, unsigned short* __restrict__ whh_bf,
                              float* __restrict__ bias) {
    int i = blockIdx.x * 256 + threadIdx.x;
    wih_bf[i] = f2bf(Wih[i]);
    whh_bf[i] = f2bf(Whh[i]);
    if (i < G_) bias[i] = bih[i] + bhh[i];
}

// ---------------------------------------------------------------------------
__global__ void prep_attn_kernel(const float* __restrict__ x, const float* __restrict__ Wattn,
                                 float* __restrict__ attn) {
    __shared__ float wx[T_];
    __shared__ float red[256];
    int b = blockIdx.x, d = threadIdx.x;
    if (d < T_) wx[d] = Wattn[2 * H_ + d];
    __syncthreads();
    const float* xb = x + (size_t)b * T_ * D_ + d;
    float s = 0.f;
    #pragma unroll
    for (int t = 0; t < T_; ++t) s += xb[t * D_] * wx[t];
    red[d] = s;
    __syncthreads();
    for (int o = 128; o > 0; o >>= 1) {
        if (d < o) red[d] = fmaxf(red[d], red[d + o]);
        __syncthreads();
    }
    float m = red[0];
    __syncthreads();
    float e = __expf(s - m);
    red[d] = e;
    __syncthreads();
    for (int o = 128; o > 0; o >>= 1) {
        if (d < o) red[d] += red[d + o];
        __syncthreads();
    }
    attn[b * D_ + d] = e * (1.f / red[0]);
}

// ---------------------------------------------------------------------------
__global__ void winw_kernel(const float* __restrict__ x, const float* __restrict__ attn,
                            float* __restrict__ w_out, unsigned short* __restrict__ win_bf) {
    int i4 = blockIdx.x * 256 + threadIdx.x;
    int e  = i4 * 4;
    int d  = e & 255;
    int bt = e >> 8;
    int b  = bt >> 6, t = bt & 63;
    f32x4 xv = *(const f32x4*)(x + e);
    f32x4 av = *(const f32x4*)(attn + b * D_ + d);
    f32x4 w  = xv * av;
    *(f32x4*)(w_out + e) = w;
    ushort4 u;
    u.x = f2bf(w[0]); u.y = f2bf(w[1]); u.z = f2bf(w[2]); u.w = f2bf(w[3]);
    *(ushort4*)(win_bf + ((size_t)(t * B_ + b) * D_ + d)) = u;
}

// ---------------------------------------------------------------------------
__global__ __launch_bounds__(256, 2) void gemmx_kernel(const unsigned short* __restrict__ A,
                                                       const unsigned short* __restrict__ Bw,
                                                       const float* __restrict__ bias,
                                                       unsigned short* __restrict__ pre) {
    int bx = blockIdx.x;
    int bn = bx & 7, bm = bx >> 3;
    int tid = threadIdx.x, lane = tid & 63, w = tid >> 6;
    int wr = w >> 1, wc = w & 1;
    int m0 = bm * 128 + wr * 64, n0 = bn * 128 + wc * 64;
    int lr = lane & 15, lk = (lane >> 4) * 8;

    const unsigned short* Ab[4];
    const unsigned short* Bb[4];
    float biasv[4];
    #pragma unroll
    for (int i = 0; i < 4; ++i) {
        Ab[i] = A  + (size_t)(m0 + i * 16 + lr) * D_ + lk;
        Bb[i] = Bw + (size_t)(n0 + i * 16 + lr) * D_ + lk;
        biasv[i] = bias[n0 + i * 16 + lr];
    }
    f32x4 acc[4][4] = {};
    #pragma unroll
    for (int kk = 0; kk < 8; ++kk) {
        bf16x8 a[4], bb[4];
        #pragma unroll
        for (int i = 0; i < 4; ++i) {
            a[i]  = *(const bf16x8*)(Ab[i] + kk * 32);
            bb[i] = *(const bf16x8*)(Bb[i] + kk * 32);
        }
        #pragma unroll
        for (int mi = 0; mi < 4; ++mi)
            #pragma unroll
            for (int ni = 0; ni < 4; ++ni)
                acc[mi][ni] = __builtin_amdgcn_mfma_f32_16x16x32_bf16(a[mi], bb[ni], acc[mi][ni], 0, 0, 0);
    }
    int orow = (lane >> 4) * 4;
    #pragma unroll
    for (int mi = 0; mi < 4; ++mi)
        #pragma unroll
        for (int ni = 0; ni < 4; ++ni)
            #pragma unroll
            for (int q = 0; q < 4; ++q) {
                int m = m0 + mi * 16 + orow + q;
                int n = n0 + ni * 16 + lr;
                pre[(size_t)m * G_ + n] = f2bf(acc[mi][ni][q] + biasv[ni]);
            }
}

// ---------------------------------------------------------------------------
// seqs ablation template. MODE bits: 1=load pre-gates, 2=load W stream,
// 4=enc stores, 8=full cell math, 16=MFMA. 31 = the real kernel.
// Variants write only to scratch (tail of pre, rewritten by gemmx each
// replay) — d_out is written only by MODE=31.
template<int MODE>
__global__ __launch_bounds__(1024)
__attribute__((amdgpu_waves_per_eu(4, 4)))
void seqs_t(const unsigned short* __restrict__ pre,
            const unsigned short* __restrict__ Whh,
            float* __restrict__ enc_out) {
    constexpr bool LPG  = (MODE & 1)  != 0;
    constexpr bool LWS  = (MODE & 2)  != 0;
    constexpr bool STO  = (MODE & 4)  != 0;
    constexpr bool CELL = (MODE & 8)  != 0;
    constexpr bool MF   = (MODE & 16) != 0;

    extern __shared__ char smem[];
    unsigned short* W_frag = (unsigned short*)smem;              // [16][8kk][64][8] = 131072 B
    unsigned short* h_frag = (unsigned short*)(smem + 131072);   // [2par][8kk][64][8] = 16384 B

    int tid = threadIdx.x, lane = tid & 63, w = tid >> 6;
    int lr = lane & 15, hi = lane >> 4;
    int r0 = blockIdx.x * 16;

    {
        const unsigned short* src = Whh + (size_t)(w * 16 + lr) * 256 + hi * 8;
        #pragma unroll
        for (int c = 0; c < 8; ++c)
            *(u32x4*)&W_frag[((w * 8 + c) * 64 + lane) * 8] = *(const u32x4*)(src + c * 32);
    }
    for (int i = tid; i < 4096; i += 1024) ((unsigned int*)h_frag)[i] = 0;

    const unsigned short* Wg1 = Whh + (size_t)(1 * 256 + w * 16 + lr) * 256 + hi * 8;
    const unsigned short* Wg2 = Whh + (size_t)(2 * 256 + w * 16 + lr) * 256 + hi * 8;
    const unsigned short* Wg3 = Whh + (size_t)(3 * 256 + w * 16 + lr) * 256 + hi * 8;
    bf16x8 sb1[4], sb2[4], sb3[4];
    #pragma unroll
    for (int k2 = 0; k2 < 4; ++k2) {
        sb1[k2] = *(const bf16x8*)(Wg1 + k2 * 32);
        sb2[k2] = *(const bf16x8*)(Wg2 + k2 * 32);
        sb3[k2] = *(const bf16x8*)(Wg3 + k2 * 32);
    }

    const unsigned short* ppair = pre + (size_t)(r0 + hi * 4) * G_ + w * 16 + (lr & 14);
    unsigned int sel = lr & 1;
    float cst[4] = {};

    __syncthreads();

    #pragma unroll 1
    for (int t = 0; t < T_; ++t) {
        unsigned int pg[16];
        if constexpr (LPG) {
            const unsigned short* Ps = ppair + (size_t)t * (1024u * 1024u);
            #pragma unroll
            for (int g = 0; g < 4; ++g)
                #pragma unroll
                for (int q = 0; q < 4; ++q)
                    pg[g * 4 + q] = *(const unsigned int*)(Ps + (size_t)q * 1024 + g * 256);
        } else {
            #pragma unroll
            for (int i = 0; i < 16; ++i) { pg[i] = 0; asm volatile("" : "+v"(pg[i])); }
        }

        int p = t & 1;
        const unsigned short* hrd = h_frag + p * 4096;
        unsigned short*       hwr = h_frag + (p ^ 1) * 4096;

        f32x4 acc[4] = {};
        #pragma unroll
        for (int kk = 0; kk < 4; ++kk) {
            bf16x8 a  = *(const bf16x8*)&hrd[(kk * 64 + lane) * 8];
            bf16x8 b0 = *(const bf16x8*)&W_frag[((w * 8 + kk) * 64 + lane) * 8];
            if constexpr (MF) {
                acc[0] = __builtin_amdgcn_mfma_f32_16x16x32_bf16(a, b0, acc[0], 0, 0, 0);
                acc[1] = __builtin_amdgcn_mfma_f32_16x16x32_bf16(a, sb1[kk], acc[1], 0, 0, 0);
                acc[2] = __builtin_amdgcn_mfma_f32_16x16x32_bf16(a, sb2[kk], acc[2], 0, 0, 0);
                acc[3] = __builtin_amdgcn_mfma_f32_16x16x32_bf16(a, sb3[kk], acc[3], 0, 0, 0);
            } else {
                asm volatile("" :: "v"(a), "v"(b0));
            }
        }
        if constexpr (LWS) {
            #pragma unroll
            for (int k2 = 0; k2 < 4; ++k2) {
                sb1[k2] = *(const bf16x8*)(Wg1 + (k2 + 4) * 32);
                sb2[k2] = *(const bf16x8*)(Wg2 + (k2 + 4) * 32);
                sb3[k2] = *(const bf16x8*)(Wg3 + (k2 + 4) * 32);
            }
        } else {
            #pragma unroll
            for (int k2 = 0; k2 < 4; ++k2)
                asm volatile("" : "+v"(sb1[k2]), "+v"(sb2[k2]), "+v"(sb3[k2]));
        }
        #pragma unroll
        for (int kk = 4; kk < 8; ++kk) {
            bf16x8 a  = *(const bf16x8*)&hrd[(kk * 64 + lane) * 8];
            bf16x8 b0 = *(const bf16x8*)&W_frag[((w * 8 + kk) * 64 + lane) * 8];
            if constexpr (MF) {
                acc[0] = __builtin_amdgcn_mfma_f32_16x16x32_bf16(a, b0, acc[0], 0, 0, 0);
                acc[1] = __builtin_amdgcn_mfma_f32_16x16x32_bf16(a, sb1[kk - 4], acc[1], 0, 0, 0);
                acc[2] = __builtin_amdgcn_mfma_f32_16x16x32_bf16(a, sb2[kk - 4], acc[2], 0, 0, 0);
                acc[3] = __builtin_amdgcn_mfma_f32_16x16x32_bf16(a, sb3[kk - 4], acc[3], 0, 0, 0);
            } else {
                asm volatile("" :: "v"(a), "v"(b0));
            }
        }
        if constexpr (LWS) {
            #pragma unroll
            for (int k2 = 0; k2 < 4; ++k2) {
                sb1[k2] = *(const bf16x8*)(Wg1 + k2 * 32);
                sb2[k2] = *(const bf16x8*)(Wg2 + k2 * 32);
                sb3[k2] = *(const bf16x8*)(Wg3 + k2 * 32);
            }
        } else {
            #pragma unroll
            for (int k2 = 0; k2 < 4; ++k2)
                asm volatile("" : "+v"(sb1[k2]), "+v"(sb2[k2]), "+v"(sb3[k2]));
        }

        #pragma unroll
        for (int q = 0; q < 4; ++q) {
            float h;
            if constexpr (CELL) {
                float gi = acc[0][q] + __builtin_bit_cast(float, sel ? (pg[0 * 4 + q] & 0xffff0000u) : (pg[0 * 4 + q] << 16));
                float gf = acc[1][q] + __builtin_bit_cast(float, sel ? (pg[1 * 4 + q] & 0xffff0000u) : (pg[1 * 4 + q] << 16));
                float gg = acc[2][q] + __builtin_bit_cast(float, sel ? (pg[2 * 4 + q] & 0xffff0000u) : (pg[2 * 4 + q] << 16));
                float go = acc[3][q] + __builtin_bit_cast(float, sel ? (pg[3 * 4 + q] & 0xffff0000u) : (pg[3 * 4 + q] << 16));
                float si = RCP(1.f + __expf(-gi));
                float sf = RCP(1.f + __expf(-gf));
                float so = RCP(1.f + __expf(-go));
                float tg = 1.f - 2.f * RCP(__expf(2.f * gg) + 1.f);
                float cn = sf * cst[q] + si * tg;
                cst[q] = cn;
                float tc = 1.f - 2.f * RCP(__expf(2.f * cn) + 1.f);
                h = so * tc;
            } else {
                if constexpr (MF) h = acc[0][q] * 0.001f;
                else              h = 0.0001f * (float)((t + q) & 7);
            }
            unsigned int hu = (unsigned int)f2bf(h);
            unsigned int dw;
            if constexpr (CELL) {
                unsigned int ph = (unsigned int)__shfl_xor((int)hu, 1);
                dw = hu | (ph << 16);
            } else {
                dw = hu | (hu << 16);
            }
            if ((lr & 1) == 0) {
                *(unsigned int*)&hwr[(w >> 1) * 512 +
                                     (((w & 1) * 2 + (lr >> 3)) * 16 + hi * 4 + q) * 8 + (lr & 7)] = dw;
            }
            if constexpr (STO)
                enc_out[((size_t)(r0 + hi * 4 + q) * T_ + t) * H_ + w * 16 + lr] = h;
            else
                asm volatile("" :: "v"(h));
        }

        asm volatile("s_waitcnt lgkmcnt(0)" ::: "memory");
        __builtin_amdgcn_s_barrier();
        __builtin_amdgcn_sched_barrier(0);
    }
}

// ---------------------------------------------------------------------------
extern "C" void kernel_launch(void* const* d_in, const int* in_sizes, int n_in,
                              void* d_out, int out_size, void* d_ws, size_t ws_size,
                              hipStream_t stream) {
    const float* x     = (const float*)d_in[0];
    const float* Wattn = (const float*)d_in[1];
    const float* Wih   = (const float*)d_in[3];
    const float* Whh   = (const float*)d_in[4];
    const float* bih   = (const float*)d_in[5];
    const float* bhh   = (const float*)d_in[6];

    char* ws = (char*)d_ws;
    float*          attn   = (float*)(ws);                            // 1 MB
    unsigned short* win_bf = (unsigned short*)(ws + 1048576);         // 32 MB [t][b][d]
    unsigned short* wih_bf = (unsigned short*)(ws + 34603008);        // 512 KB
    unsigned short* whh_bf = (unsigned short*)(ws + 35127296);        // 512 KB
    float*          bias   = (float*)(ws + 35651584);                 // 4 KB
    unsigned short* pre    = (unsigned short*)(ws + 35659776);        // 128 MB [t][b][n]
    float*          enc_sc = (float*)(ws + 35659776 + 67108864);      // 64 MB scratch (tail of pre)

    float* w_out   = (float*)d_out;
    float* enc_out = (float*)d_out + (size_t)B_ * T_ * D_;

    hipFuncSetAttribute((const void*)seqs_t<31>, hipFuncAttributeMaxDynamicSharedMemorySize, 147456);
    hipFuncSetAttribute((const void*)seqs_t<30>, hipFuncAttributeMaxDynamicSharedMemorySize, 147456);
    hipFuncSetAttribute((const void*)seqs_t<29>, hipFuncAttributeMaxDynamicSharedMemorySize, 147456);
    hipFuncSetAttribute((const void*)seqs_t<27>, hipFuncAttributeMaxDynamicSharedMemorySize, 147456);
    hipFuncSetAttribute((const void*)seqs_t<16>, hipFuncAttributeMaxDynamicSharedMemorySize, 147456);
    hipFuncSetAttribute((const void*)seqs_t<0>,  hipFuncAttributeMaxDynamicSharedMemorySize, 147456);

    prep_w_kernel<<<dim3(1024), dim3(256), 0, stream>>>(Wih, Whh, bih, bhh, wih_bf, whh_bf, bias);
    prep_attn_kernel<<<dim3(1024), dim3(256), 0, stream>>>(x, Wattn, attn);
    winw_kernel<<<dim3(16384), dim3(256), 0, stream>>>(x, attn, w_out, win_bf);
    gemmx_kernel<<<dim3(4096), dim3(256), 0, stream>>>(win_bf, wih_bf, bias, pre);

    // real
    seqs_t<31><<<dim3(64), dim3(1024), 147456, stream>>>(pre, whh_bf, enc_out);
    // ablations (scratch only; pre tail is rewritten by gemmx every replay)
    seqs_t<30><<<dim3(64), dim3(1024), 147456, stream>>>(pre, whh_bf, enc_sc);  // B: no pre loads
    seqs_t<29><<<dim3(64), dim3(1024), 147456, stream>>>(pre, whh_bf, enc_sc);  // C: no W stream
    seqs_t<27><<<dim3(64), dim3(1024), 147456, stream>>>(pre, whh_bf, enc_sc);  // D: no enc stores
    seqs_t<16><<<dim3(64), dim3(1024), 147456, stream>>>(pre, whh_bf, enc_sc);  // E: MFMA+LDS only
    seqs_t<0> <<<dim3(64), dim3(1024), 147456, stream>>>(pre, whh_bf, enc_sc);  // F: skeleton
}

// Round 13
// 474.382 us; speedup vs baseline: 3.7527x; 3.7527x over previous
//
#include <hip/hip_runtime.h>
#include <hip/hip_bf16.h>
#include <stdint.h>

// Problem constants
#define B_ 1024
#define T_ 64
#define D_ 256
#define H_ 256
#define G_ 1024   // 4*H

typedef float f32x4 __attribute__((ext_vector_type(4)));
typedef __bf16 bf16x8 __attribute__((ext_vector_type(8)));
typedef unsigned int u32x4 __attribute__((ext_vector_type(4)));

#if __has_builtin(__builtin_amdgcn_rcpf)
#define RCP(x) __builtin_amdgcn_rcpf(x)
#else
#define RCP(x) (1.f / (x))
#endif

__device__ __forceinline__ float bf2f(unsigned int u) {
    unsigned int x = u << 16;
    return __builtin_bit_cast(float, x);
}
__device__ __forceinline__ unsigned short f2bf(float f) {
    __hip_bfloat16 h = __float2bfloat16(f);   // RNE
    return __builtin_bit_cast(unsigned short, h);
}

// ---------------------------------------------------------------------------
__global__ void prep_w_kernel(const float* __restrict__ Wih, const float* __restrict__ Whh,
                              const float* __restrict__ bih, const float* __restrict__ bhh,
                              unsigned short* __restrict__ wih_bf, unsigned short* __restrict__ whh_bf,
                              float* __restrict__ bias) {
    int i = blockIdx.x * 256 + threadIdx.x;
    wih_bf[i] = f2bf(Wih[i]);
    whh_bf[i] = f2bf(Whh[i]);
    if (i < G_) bias[i] = bih[i] + bhh[i];
}

// ---------------------------------------------------------------------------
__global__ void prep_attn_kernel(const float* __restrict__ x, const float* __restrict__ Wattn,
                                 float* __restrict__ attn) {
    __shared__ float wx[T_];
    __shared__ float red[256];
    int b = blockIdx.x, d = threadIdx.x;
    if (d < T_) wx[d] = Wattn[2 * H_ + d];
    __syncthreads();
    const float* xb = x + (size_t)b * T_ * D_ + d;
    float s = 0.f;
    #pragma unroll
    for (int t = 0; t < T_; ++t) s += xb[t * D_] * wx[t];
    red[d] = s;
    __syncthreads();
    for (int o = 128; o > 0; o >>= 1) {
        if (d < o) red[d] = fmaxf(red[d], red[d + o]);
        __syncthreads();
    }
    float m = red[0];
    __syncthreads();
    float e = __expf(s - m);
    red[d] = e;
    __syncthreads();
    for (int o = 128; o > 0; o >>= 1) {
        if (d < o) red[d] += red[d + o];
        __syncthreads();
    }
    attn[b * D_ + d] = e * (1.f / red[0]);
}

// ---------------------------------------------------------------------------
__global__ void winw_kernel(const float* __restrict__ x, const float* __restrict__ attn,
                            float* __restrict__ w_out, unsigned short* __restrict__ win_bf) {
    int i4 = blockIdx.x * 256 + threadIdx.x;
    int e  = i4 * 4;
    int d  = e & 255;
    int bt = e >> 8;
    int b  = bt >> 6, t = bt & 63;
    f32x4 xv = *(const f32x4*)(x + e);
    f32x4 av = *(const f32x4*)(attn + b * D_ + d);
    f32x4 w  = xv * av;
    *(f32x4*)(w_out + e) = w;
    ushort4 u;
    u.x = f2bf(w[0]); u.y = f2bf(w[1]); u.z = f2bf(w[2]); u.w = f2bf(w[3]);
    *(ushort4*)(win_bf + ((size_t)(t * B_ + b) * D_ + d)) = u;
}

// ---------------------------------------------------------------------------
// gemmx v12: coalesced epilogue. C-tile staged in LDS (pitch 136 shorts),
// then written as 256 B contiguous row-chunks (was: 64 scattered 32 B writes).
__global__ __launch_bounds__(256, 2) void gemmx_kernel(const unsigned short* __restrict__ A,
                                                       const unsigned short* __restrict__ Bw,
                                                       const float* __restrict__ bias,
                                                       unsigned short* __restrict__ pre) {
    __shared__ unsigned short ctile[128 * 136];   // 34816 B
    int bx = blockIdx.x;
    int bn = bx & 7, bm = bx >> 3;
    int tid = threadIdx.x, lane = tid & 63, w = tid >> 6;
    int wr = w >> 1, wc = w & 1;
    int m0 = bm * 128 + wr * 64, n0 = bn * 128 + wc * 64;
    int lr = lane & 15, lk = (lane >> 4) * 8;

    const unsigned short* Ab[4];
    const unsigned short* Bb[4];
    float biasv[4];
    #pragma unroll
    for (int i = 0; i < 4; ++i) {
        Ab[i] = A  + (size_t)(m0 + i * 16 + lr) * D_ + lk;
        Bb[i] = Bw + (size_t)(n0 + i * 16 + lr) * D_ + lk;
        biasv[i] = bias[n0 + i * 16 + lr];
    }
    f32x4 acc[4][4] = {};
    #pragma unroll
    for (int kk = 0; kk < 8; ++kk) {
        bf16x8 a[4], bb[4];
        #pragma unroll
        for (int i = 0; i < 4; ++i) {
            a[i]  = *(const bf16x8*)(Ab[i] + kk * 32);
            bb[i] = *(const bf16x8*)(Bb[i] + kk * 32);
        }
        #pragma unroll
        for (int mi = 0; mi < 4; ++mi)
            #pragma unroll
            for (int ni = 0; ni < 4; ++ni)
                acc[mi][ni] = __builtin_amdgcn_mfma_f32_16x16x32_bf16(a[mi], bb[ni], acc[mi][ni], 0, 0, 0);
    }
    int orow = (lane >> 4) * 4;
    // stage to LDS (local 128x128 tile)
    #pragma unroll
    for (int mi = 0; mi < 4; ++mi)
        #pragma unroll
        for (int ni = 0; ni < 4; ++ni)
            #pragma unroll
            for (int q = 0; q < 4; ++q) {
                int lrow = wr * 64 + mi * 16 + orow + q;
                int lcol = wc * 64 + ni * 16 + lr;
                ctile[lrow * 136 + lcol] = f2bf(acc[mi][ni][q] + biasv[ni]);
            }
    __syncthreads();
    // coalesced write: 16 lanes cover one row's 256 B chunk
    #pragma unroll
    for (int rep = 0; rep < 8; ++rep) {
        int idx  = rep * 256 + tid;
        int lrow = idx >> 4, c16 = idx & 15;
        u32x4 v = *(const u32x4*)&ctile[lrow * 136 + c16 * 8];
        *(u32x4*)(pre + (size_t)(bm * 128 + lrow) * G_ + bn * 128 + c16 * 8) = v;
    }
}

// ---------------------------------------------------------------------------
// seqs v12: v11 + coalesced enc stores. Cell writes h only to LDS (h_frag);
// after the end-of-step barrier each wave stores its row of h(t) as ONE
// contiguous 1 KB segment (float4/lane) re-read from LDS. Removes the
// 4x64B-scattered store stream that the round-12 ablation identified as the
// bottleneck (MODE 30 = stores-without-loads ran at 90 GB/s, 734 us).
__global__ __launch_bounds__(1024)
__attribute__((amdgpu_waves_per_eu(4, 4)))
void seqs_kernel(const unsigned short* __restrict__ pre,
                 const unsigned short* __restrict__ Whh,
                 float* __restrict__ enc_out) {
    extern __shared__ char smem[];
    unsigned short* W_frag = (unsigned short*)smem;              // [16][8kk][64][8] = 131072 B
    unsigned short* h_frag = (unsigned short*)(smem + 131072);   // [2par][8kk][64][8] = 16384 B

    int tid = threadIdx.x, lane = tid & 63, w = tid >> 6;   // w in [0,16)
    int lr = lane & 15, hi = lane >> 4;
    int r0 = blockIdx.x * 16;

    // stage g=0 tile (B-row n = w*16 + lr) into LDS fragment layout
    {
        const unsigned short* src = Whh + (size_t)(w * 16 + lr) * 256 + hi * 8;
        #pragma unroll
        for (int c = 0; c < 8; ++c)
            *(u32x4*)&W_frag[((w * 8 + c) * 64 + lane) * 8] = *(const u32x4*)(src + c * 32);
    }
    for (int i = tid; i < 4096; i += 1024) ((unsigned int*)h_frag)[i] = 0;

    const unsigned short* Wg1 = Whh + (size_t)(1 * 256 + w * 16 + lr) * 256 + hi * 8;
    const unsigned short* Wg2 = Whh + (size_t)(2 * 256 + w * 16 + lr) * 256 + hi * 8;
    const unsigned short* Wg3 = Whh + (size_t)(3 * 256 + w * 16 + lr) * 256 + hi * 8;
    bf16x8 sb1[4], sb2[4], sb3[4];
    #pragma unroll
    for (int k2 = 0; k2 < 4; ++k2) {
        sb1[k2] = *(const bf16x8*)(Wg1 + k2 * 32);
        sb2[k2] = *(const bf16x8*)(Wg2 + k2 * 32);
        sb3[k2] = *(const bf16x8*)(Wg3 + k2 * 32);
    }

    const unsigned short* ppair = pre + (size_t)(r0 + hi * 4) * G_ + w * 16 + (lr & 14);
    unsigned int sel = lr & 1;
    float cst[4] = {};

    // store-phase LDS index: row w, cols lane*4..lane*4+3 (same kk/lane'/e block)
    int sc = (lane >> 3) * 512 + (((lane >> 1) & 3) * 16 + w) * 8 + (lane & 1) * 4;

    __syncthreads();

    #pragma unroll 1
    for (int t = 0; t < T_; ++t) {
        const unsigned short* Ps = ppair + (size_t)t * (1024u * 1024u);
        unsigned int pg[16];
        #pragma unroll
        for (int g = 0; g < 4; ++g)
            #pragma unroll
            for (int q = 0; q < 4; ++q)
                pg[g * 4 + q] = *(const unsigned int*)(Ps + (size_t)q * 1024 + g * 256);

        int p = t & 1;
        const unsigned short* hrd = h_frag + p * 4096;
        unsigned short*       hwr = h_frag + (p ^ 1) * 4096;

        f32x4 acc[4] = {};
        #pragma unroll
        for (int kk = 0; kk < 4; ++kk) {
            bf16x8 a  = *(const bf16x8*)&hrd[(kk * 64 + lane) * 8];
            bf16x8 b0 = *(const bf16x8*)&W_frag[((w * 8 + kk) * 64 + lane) * 8];
            acc[0] = __builtin_amdgcn_mfma_f32_16x16x32_bf16(a, b0, acc[0], 0, 0, 0);
            acc[1] = __builtin_amdgcn_mfma_f32_16x16x32_bf16(a, sb1[kk], acc[1], 0, 0, 0);
            acc[2] = __builtin_amdgcn_mfma_f32_16x16x32_bf16(a, sb2[kk], acc[2], 0, 0, 0);
            acc[3] = __builtin_amdgcn_mfma_f32_16x16x32_bf16(a, sb3[kk], acc[3], 0, 0, 0);
        }
        #pragma unroll
        for (int k2 = 0; k2 < 4; ++k2) {
            sb1[k2] = *(const bf16x8*)(Wg1 + (k2 + 4) * 32);
            sb2[k2] = *(const bf16x8*)(Wg2 + (k2 + 4) * 32);
            sb3[k2] = *(const bf16x8*)(Wg3 + (k2 + 4) * 32);
        }
        #pragma unroll
        for (int kk = 4; kk < 8; ++kk) {
            bf16x8 a  = *(const bf16x8*)&hrd[(kk * 64 + lane) * 8];
            bf16x8 b0 = *(const bf16x8*)&W_frag[((w * 8 + kk) * 64 + lane) * 8];
            acc[0] = __builtin_amdgcn_mfma_f32_16x16x32_bf16(a, b0, acc[0], 0, 0, 0);
            acc[1] = __builtin_amdgcn_mfma_f32_16x16x32_bf16(a, sb1[kk - 4], acc[1], 0, 0, 0);
            acc[2] = __builtin_amdgcn_mfma_f32_16x16x32_bf16(a, sb2[kk - 4], acc[2], 0, 0, 0);
            acc[3] = __builtin_amdgcn_mfma_f32_16x16x32_bf16(a, sb3[kk - 4], acc[3], 0, 0, 0);
        }
        #pragma unroll
        for (int k2 = 0; k2 < 4; ++k2) {
            sb1[k2] = *(const bf16x8*)(Wg1 + k2 * 32);
            sb2[k2] = *(const bf16x8*)(Wg2 + k2 * 32);
            sb3[k2] = *(const bf16x8*)(Wg3 + k2 * 32);
        }

        // cell update: h -> LDS only (no global scatter)
        #pragma unroll
        for (int q = 0; q < 4; ++q) {
            float gi = acc[0][q] + __builtin_bit_cast(float, sel ? (pg[0 * 4 + q] & 0xffff0000u) : (pg[0 * 4 + q] << 16));
            float gf = acc[1][q] + __builtin_bit_cast(float, sel ? (pg[1 * 4 + q] & 0xffff0000u) : (pg[1 * 4 + q] << 16));
            float gg = acc[2][q] + __builtin_bit_cast(float, sel ? (pg[2 * 4 + q] & 0xffff0000u) : (pg[2 * 4 + q] << 16));
            float go = acc[3][q] + __builtin_bit_cast(float, sel ? (pg[3 * 4 + q] & 0xffff0000u) : (pg[3 * 4 + q] << 16));
            float si = RCP(1.f + __expf(-gi));
            float sf = RCP(1.f + __expf(-gf));
            float so = RCP(1.f + __expf(-go));
            float tg = 1.f - 2.f * RCP(__expf(2.f * gg) + 1.f);
            float cn = sf * cst[q] + si * tg;
            cst[q] = cn;
            float tc = 1.f - 2.f * RCP(__expf(2.f * cn) + 1.f);
            float h  = so * tc;
            unsigned int hu = (unsigned int)f2bf(h);
            unsigned int ph = (unsigned int)__shfl_xor((int)hu, 1);
            if ((lr & 1) == 0) {
                unsigned int dw = hu | (ph << 16);
                *(unsigned int*)&hwr[(w >> 1) * 512 +
                                     (((w & 1) * 2 + (lr >> 3)) * 16 + hi * 4 + q) * 8 + (lr & 7)] = dw;
            }
        }

        // drain LDS writes, barrier: h(t) complete & visible
        asm volatile("s_waitcnt lgkmcnt(0)" ::: "memory");
        __builtin_amdgcn_s_barrier();

        // coalesced store: wave w stores row r0+w of h(t) as 1 KB contiguous
        {
            ushort4 hv = *(const ushort4*)&hwr[sc];
            f32x4 fv;
            fv[0] = bf2f(hv.x); fv[1] = bf2f(hv.y); fv[2] = bf2f(hv.z); fv[3] = bf2f(hv.w);
            *(f32x4*)(enc_out + ((size_t)(r0 + w) * T_ + t) * H_ + lane * 4) = fv;
        }
        __builtin_amdgcn_sched_barrier(0);
    }
}

// ---------------------------------------------------------------------------
extern "C" void kernel_launch(void* const* d_in, const int* in_sizes, int n_in,
                              void* d_out, int out_size, void* d_ws, size_t ws_size,
                              hipStream_t stream) {
    const float* x     = (const float*)d_in[0];
    const float* Wattn = (const float*)d_in[1];
    // d_in[2] = b_attn (cancels in softmax)
    const float* Wih   = (const float*)d_in[3];
    const float* Whh   = (const float*)d_in[4];
    const float* bih   = (const float*)d_in[5];
    const float* bhh   = (const float*)d_in[6];

    char* ws = (char*)d_ws;
    float*          attn   = (float*)(ws);                            // 1 MB
    unsigned short* win_bf = (unsigned short*)(ws + 1048576);         // 32 MB [t][b][d]
    unsigned short* wih_bf = (unsigned short*)(ws + 34603008);        // 512 KB
    unsigned short* whh_bf = (unsigned short*)(ws + 35127296);        // 512 KB
    float*          bias   = (float*)(ws + 35651584);                 // 4 KB
    unsigned short* pre    = (unsigned short*)(ws + 35659776);        // 128 MB [t][b][n]

    float* w_out   = (float*)d_out;                                   // output 0
    float* enc_out = (float*)d_out + (size_t)B_ * T_ * D_;            // output 1

    hipFuncSetAttribute((const void*)seqs_kernel,
                        hipFuncAttributeMaxDynamicSharedMemorySize, 147456);

    prep_w_kernel<<<dim3(1024), dim3(256), 0, stream>>>(Wih, Whh, bih, bhh, wih_bf, whh_bf, bias);
    prep_attn_kernel<<<dim3(1024), dim3(256), 0, stream>>>(x, Wattn, attn);
    winw_kernel<<<dim3(16384), dim3(256), 0, stream>>>(x, attn, w_out, win_bf);
    gemmx_kernel<<<dim3(4096), dim3(256), 0, stream>>>(win_bf, wih_bf, bias, pre);
    seqs_kernel<<<dim3(64), dim3(1024), 147456, stream>>>(pre, whh_bf, enc_out);
}